// Round 1
// baseline (3248.666 us; speedup 1.0000x reference)
//
#include <hip/hip_runtime.h>
#include <hip/hip_bf16.h>
#include <math.h>

#define LSEQ 2048
#define KNB 64
#define BATCH 8
#define EMB 16
#define H1 128
#define H2 128
#define MRBF 7

// ---------------------------------------------------------------------------
// Kernel 1: exact top-K=64 nearest neighbors per (b,i) via radix select.
// One 256-thread block per row. Squared distances (order == distance order)
// into LDS, 4x 8-bit-digit radix passes on the float bit pattern (non-negative
// floats compare identically as uints), then compaction of the 64 winners.
// ---------------------------------------------------------------------------
__global__ __launch_bounds__(256) void topk_kernel(
    const float* __restrict__ R, int* __restrict__ nbr)
{
    const int bi = blockIdx.x;          // b*LSEQ + i
    const int i  = bi & (LSEQ - 1);
    const int bL = bi & ~(LSEQ - 1);    // b*LSEQ
    const int tid = threadIdx.x;

    __shared__ float d2s[LSEQ];
    __shared__ unsigned hist[256];
    __shared__ unsigned scanb[256];
    __shared__ unsigned s_digit, s_excl;
    __shared__ int outPos, tieCnt;

    const float xi = R[bi*3+0];
    const float yi = R[bi*3+1];
    const float zi = R[bi*3+2];

    for (int j = tid; j < LSEQ; j += 256) {
        float dx = xi - R[(bL+j)*3+0];
        float dy = yi - R[(bL+j)*3+1];
        float dz = zi - R[(bL+j)*3+2];
        float d2 = dx*dx + dy*dy + dz*dz;
        int dd = j - i; if (dd < 0) dd = -dd;
        if (dd <= 3) d2 = __uint_as_float(0x7f800000u);  // +inf: bonded/self excluded
        d2s[j] = d2;
    }
    if (tid == 0) { outPos = 0; tieCnt = 0; }

    unsigned prefix = 0;
    int want = KNB;  // how many elements still to take within current prefix group

    for (int p = 0; p < 4; p++) {
        const int shift = 24 - 8*p;
        hist[tid] = 0u;
        __syncthreads();
        for (int j = tid; j < LSEQ; j += 256) {
            unsigned u = __float_as_uint(d2s[j]);
            bool ok = (p == 0) || (((u ^ prefix) >> (shift + 8)) == 0u);
            if (ok) atomicAdd(&hist[(u >> shift) & 255u], 1u);
        }
        __syncthreads();
        unsigned v = hist[tid];
        scanb[tid] = v;
        __syncthreads();
        // Hillis-Steele inclusive scan over 256 bins
        #pragma unroll
        for (int off = 1; off < 256; off <<= 1) {
            unsigned add = (tid >= off) ? scanb[tid - off] : 0u;
            __syncthreads();
            scanb[tid] += add;
            __syncthreads();
        }
        unsigned incl = scanb[tid];
        unsigned excl = incl - v;
        if ((int)excl < want && want <= (int)incl) { s_digit = (unsigned)tid; s_excl = excl; }
        __syncthreads();
        prefix |= s_digit << shift;
        want   -= (int)s_excl;
        __syncthreads();
    }

    const unsigned T = prefix;      // exact bit pattern of the 64th smallest d2
    const int wantTies = want;      // how many ==T elements to take
    const int outBase = bi * KNB;

    for (int j = tid; j < LSEQ; j += 256) {
        unsigned u = __float_as_uint(d2s[j]);
        if (u < T) {
            int pos = atomicAdd(&outPos, 1);
            nbr[outBase + pos] = j;
        } else if (u == T) {
            int t = atomicAdd(&tieCnt, 1);
            if (t < wantTies) {
                int pos = atomicAdd(&outPos, 1);
                nbr[outBase + pos] = j;
            }
        }
    }
}

// ---------------------------------------------------------------------------
// Kernel 2: pair MLP + RBF attraction + smooth switch, fp32.
// 128 threads = one pair per iteration; thread n owns W1[:,n], W2[:,n], W3[n,:]
// in registers. Pairs with r >= R_CUT contribute exactly 0 (smoothstep) -> skip.
// ---------------------------------------------------------------------------
__global__ __launch_bounds__(128, 2) void mlp_kernel(
    const float* __restrict__ R, const int* __restrict__ seq,
    const float* __restrict__ emb,
    const float* __restrict__ W1, const float* __restrict__ b1,
    const float* __restrict__ W2, const float* __restrict__ b2,
    const float* __restrict__ W3, const float* __restrict__ b3,
    const float* __restrict__ centers, const float* __restrict__ widths,
    const int* __restrict__ nbr, float* __restrict__ out)
{
    const int n = threadIdx.x;  // 0..127 = output neuron id

    float w1c[48];
    #pragma unroll
    for (int k = 0; k < 48; k++) w1c[k] = W1[k*H1 + n];
    float w2c[H1];
    #pragma unroll
    for (int k = 0; k < H1; k++) w2c[k] = W2[k*H2 + n];
    float w3r[MRBF];
    #pragma unroll
    for (int m = 0; m < MRBF; m++) w3r[m] = W3[n*MRBF + m];
    const float b1n = b1[n];
    const float b2n = b2[n];

    __shared__ float xs[48];
    __shared__ float hs[H2];
    __shared__ float red[2][8];
    __shared__ float arr7[8];
    __shared__ float bacc[BATCH];
    if (n < BATCH) bacc[n] = 0.f;
    __syncthreads();

    const int total = BATCH * LSEQ * KNB;
    for (int p = blockIdx.x; p < total; p += gridDim.x) {
        const int bi = p >> 6;             // b*LSEQ + i
        const int j  = nbr[p];
        const int b  = bi >> 11;
        const int bL = b << 11;

        // r recomputed (R is cache-resident); identical fp ops in all lanes.
        float dx = R[bi*3+0] - R[(bL+j)*3+0];
        float dy = R[bi*3+1] - R[(bL+j)*3+1];
        float dz = R[bi*3+2] - R[(bL+j)*3+2];
        float r = sqrtf(dx*dx + dy*dy + dz*dz + 1e-12f);
        if (r >= 12.0f) continue;          // smooth_switch == 0 exactly

        const int si = seq[bi];
        const int sj = seq[bL + j];
        if (n < EMB) {
            float a = emb[si*EMB + n];
            float e = emb[sj*EMB + n];
            xs[n] = a; xs[EMB+n] = e; xs[2*EMB+n] = a*e;
        }
        __syncthreads();

        float acc = b1n;
        #pragma unroll
        for (int k = 0; k < 48; k++) acc = fmaf(xs[k], w1c[k], acc);
        hs[n] = fmaxf(acc, 0.f);
        __syncthreads();

        float acc2 = b2n;
        #pragma unroll
        for (int k = 0; k < H1; k++) acc2 = fmaf(hs[k], w2c[k], acc2);
        float h2 = fmaxf(acc2, 0.f);

        float pm[MRBF];
        #pragma unroll
        for (int m = 0; m < MRBF; m++) pm[m] = h2 * w3r[m];
        #pragma unroll
        for (int off = 32; off > 0; off >>= 1) {
            #pragma unroll
            for (int m = 0; m < MRBF; m++) pm[m] += __shfl_down(pm[m], off, 64);
        }
        if ((n & 63) == 0) {
            #pragma unroll
            for (int m = 0; m < MRBF; m++) red[n >> 6][m] = pm[m];
        }
        __syncthreads();

        if (n < MRBF) {
            float logit = red[0][n] + red[1][n] + b3[n];
            // softplus == logaddexp(x,0): exact-safe form
            float wm = fmaxf(logit, 0.f) + log1pf(expf(-fabsf(logit)));
            float d  = r - centers[n];
            float wd = widths[n];
            float phi = expf(-(d*d) / (2.f*wd*wd));
            arr7[n] = wm * phi;
        }
        __syncthreads();

        if (n == 0) {
            float att = 0.f;
            #pragma unroll
            for (int m = 0; m < MRBF; m++) att += arr7[m];
            float t = (r - 10.0f) * 0.5f;
            t = fminf(fmaxf(t, 0.f), 1.f);
            float sw = 1.f - t*t*(3.f - 2.f*t);
            bacc[b] += (-att) * sw;
        }
        // next iteration's shared writes are separated by >=1 barrier from all
        // reads above (xs/hs protected by the h1/h2 barriers; red/arr7 by their
        // own barriers) -- no extra barrier needed here.
    }
    __syncthreads();
    if (n < BATCH) atomicAdd(&out[n], bacc[n]);
}

// ---------------------------------------------------------------------------
extern "C" void kernel_launch(void* const* d_in, const int* in_sizes, int n_in,
                              void* d_out, int out_size, void* d_ws, size_t ws_size,
                              hipStream_t stream) {
    const float* R       = (const float*)d_in[0];
    const int*   seq     = (const int*)  d_in[1];
    const float* emb     = (const float*)d_in[2];
    const float* W1      = (const float*)d_in[3];
    const float* b1      = (const float*)d_in[4];
    const float* W2      = (const float*)d_in[5];
    const float* b2      = (const float*)d_in[6];
    const float* W3      = (const float*)d_in[7];
    const float* b3      = (const float*)d_in[8];
    const float* centers = (const float*)d_in[9];
    const float* widths  = (const float*)d_in[10];
    float* out = (float*)d_out;
    int*   nbr = (int*)d_ws;   // BATCH*LSEQ*KNB ints = 4 MiB

    hipMemsetAsync(d_out, 0, out_size * sizeof(float), stream);

    topk_kernel<<<BATCH*LSEQ, 256, 0, stream>>>(R, nbr);
    mlp_kernel<<<2048, 128, 0, stream>>>(R, seq, emb, W1, b1, W2, b2, W3, b3,
                                         centers, widths, nbr, out);
}

// Round 2
// 383.300 us; speedup vs baseline: 8.4755x; 8.4755x over previous
//
#include <hip/hip_runtime.h>
#include <math.h>

#define LSEQ 2048
#define KNB 64
#define BATCH 8
#define H1DIM 128
#define MRBF 7
#define NPAIRS (BATCH*LSEQ*KNB)
#define NTILES (NPAIRS/128)

typedef __attribute__((ext_vector_type(8))) short short8;
typedef __attribute__((ext_vector_type(4))) float floatx4;

__device__ __forceinline__ unsigned short f2bf(float f) {
    unsigned u = __float_as_uint(f);
    u += 0x7fffu + ((u >> 16) & 1u);   // round-to-nearest-even
    return (unsigned short)(u >> 16);
}

// ---------------------------------------------------------------------------
// Kernel 1: exact top-K=64 nearest neighbors per (b,i) via radix select.
// (unchanged from round 1 -- not yet the bottleneck; will profile this round)
// ---------------------------------------------------------------------------
__global__ __launch_bounds__(256) void topk_kernel(
    const float* __restrict__ R, int* __restrict__ nbr)
{
    const int bi = blockIdx.x;
    const int i  = bi & (LSEQ - 1);
    const int bL = bi & ~(LSEQ - 1);
    const int tid = threadIdx.x;

    __shared__ float d2s[LSEQ];
    __shared__ unsigned hist[256];
    __shared__ unsigned scanb[256];
    __shared__ unsigned s_digit, s_excl;
    __shared__ int outPos, tieCnt;

    const float xi = R[bi*3+0];
    const float yi = R[bi*3+1];
    const float zi = R[bi*3+2];

    for (int j = tid; j < LSEQ; j += 256) {
        float dx = xi - R[(bL+j)*3+0];
        float dy = yi - R[(bL+j)*3+1];
        float dz = zi - R[(bL+j)*3+2];
        float d2 = dx*dx + dy*dy + dz*dz;
        int dd = j - i; if (dd < 0) dd = -dd;
        if (dd <= 3) d2 = __uint_as_float(0x7f800000u);
        d2s[j] = d2;
    }
    if (tid == 0) { outPos = 0; tieCnt = 0; }

    unsigned prefix = 0;
    int want = KNB;

    for (int p = 0; p < 4; p++) {
        const int shift = 24 - 8*p;
        hist[tid] = 0u;
        __syncthreads();
        for (int j = tid; j < LSEQ; j += 256) {
            unsigned u = __float_as_uint(d2s[j]);
            bool ok = (p == 0) || (((u ^ prefix) >> (shift + 8)) == 0u);
            if (ok) atomicAdd(&hist[(u >> shift) & 255u], 1u);
        }
        __syncthreads();
        unsigned v = hist[tid];
        scanb[tid] = v;
        __syncthreads();
        #pragma unroll
        for (int off = 1; off < 256; off <<= 1) {
            unsigned add = (tid >= off) ? scanb[tid - off] : 0u;
            __syncthreads();
            scanb[tid] += add;
            __syncthreads();
        }
        unsigned incl = scanb[tid];
        unsigned excl = incl - v;
        if ((int)excl < want && want <= (int)incl) { s_digit = (unsigned)tid; s_excl = excl; }
        __syncthreads();
        prefix |= s_digit << shift;
        want   -= (int)s_excl;
        __syncthreads();
    }

    const unsigned T = prefix;
    const int wantTies = want;
    const int outBase = bi * KNB;

    for (int j = tid; j < LSEQ; j += 256) {
        unsigned u = __float_as_uint(d2s[j]);
        if (u < T) {
            int pos = atomicAdd(&outPos, 1);
            nbr[outBase + pos] = j;
        } else if (u == T) {
            int t = atomicAdd(&tieCnt, 1);
            if (t < wantTies) {
                int pos = atomicAdd(&outPos, 1);
                nbr[outBase + pos] = j;
            }
        }
    }
}

// ---------------------------------------------------------------------------
// Kernel 2: pair MLP via bf16 MFMA. 256 threads = 4 waves per block; each
// block processes 128-pair tiles. Weight fragments live in registers for the
// whole kernel. X (128x64, padded K) and H (128x128, +8 pad) staged in LDS.
// mfma_f32_16x16x32_bf16 layouts (m89/m120-verified):
//   A[m][k]: m=lane&15, k=quad*8+j  (8 contiguous k -> ds_read_b128)
//   B[k][n]: n=lane&15, k=quad*8+j
//   D[r][c]: c=lane&15, r=quad*4+reg
// ---------------------------------------------------------------------------
__global__ __launch_bounds__(256, 2) void mlp_mfma_kernel(
    const float* __restrict__ R, const int* __restrict__ seq,
    const float* __restrict__ emb,
    const float* __restrict__ W1, const float* __restrict__ b1,
    const float* __restrict__ W2, const float* __restrict__ b2,
    const float* __restrict__ W3, const float* __restrict__ b3,
    const float* __restrict__ centers, const float* __restrict__ widths,
    const int* __restrict__ nbr, float* __restrict__ out)
{
    __shared__ __align__(16) unsigned short Xs[128*72];   // X: stride 72 bf16
    __shared__ __align__(16) unsigned short Hs[128*136];  // H1/H2: stride 136 bf16
    __shared__ float r_s[128];
    __shared__ float bacc[BATCH];

    const int tid  = threadIdx.x;
    const int lane = tid & 63;
    const int wv   = tid >> 6;     // wave id 0..3
    const int l15  = lane & 15;
    const int q    = lane >> 4;    // quad

    // ---- persistent register weight fragments ----
    short8 w1f[2][2];   // [nt][kt], wave wv owns n-tiles {2wv, 2wv+1}
    short8 w2f[2][4];
    short8 w3f[4];      // [kt], single padded n-tile (cols 0..6 valid)
    float  b1v[2], b2v[2];
    #pragma unroll
    for (int nt = 0; nt < 2; nt++) {
        int n = (2*wv + nt)*16 + l15;
        b1v[nt] = b1[n]; b2v[nt] = b2[n];
        #pragma unroll
        for (int kt = 0; kt < 2; kt++)
            #pragma unroll
            for (int j = 0; j < 8; j++) {
                int k = kt*32 + q*8 + j;
                w1f[nt][kt][j] = (short)((k < 48) ? f2bf(W1[k*H1DIM + n]) : 0);
            }
        #pragma unroll
        for (int kt = 0; kt < 4; kt++)
            #pragma unroll
            for (int j = 0; j < 8; j++) {
                int k = kt*32 + q*8 + j;
                w2f[nt][kt][j] = (short)f2bf(W2[k*H1DIM + n]);
            }
    }
    #pragma unroll
    for (int kt = 0; kt < 4; kt++)
        #pragma unroll
        for (int j = 0; j < 8; j++) {
            int k = kt*32 + q*8 + j;
            w3f[kt][j] = (short)((l15 < MRBF) ? f2bf(W3[k*MRBF + l15]) : 0);
        }
    const float b3v = (l15 < MRBF) ? b3[l15] : 0.f;
    const float cen = (l15 < MRBF) ? centers[l15] : 0.f;
    const float wdt = (l15 < MRBF) ? widths[l15] : 1.f;
    const float i2w = 0.5f / (wdt*wdt);

    if (tid < BATCH) bacc[tid] = 0.f;

    for (int tile = blockIdx.x; tile < NTILES; tile += gridDim.x) {
        __syncthreads();   // previous iteration's Xs/r_s/Hs readers done

        // ---- build X: [e_i | e_j | e_i*e_j | 0-pad], bf16 ----
        {
            int pl = tid >> 1, half = tid & 1;
            int p  = tile*128 + pl;
            int bi = p >> 6;
            int b  = p >> 17;
            int jn = nbr[p];
            int rowj = (b << 11) + jn;
            int si = seq[bi], sj = seq[rowj];
            const float* ei = emb + si*16 + half*8;
            const float* ej = emb + sj*16 + half*8;
            short8 se, sn, sp, zz;
            #pragma unroll
            for (int f = 0; f < 8; f++) {
                float a = ei[f], c = ej[f];
                se[f] = (short)f2bf(a);
                sn[f] = (short)f2bf(c);
                sp[f] = (short)f2bf(a*c);
                zz[f] = 0;
            }
            int base = pl*72 + half*8;
            *(short8*)&Xs[base +  0] = se;
            *(short8*)&Xs[base + 16] = sn;
            *(short8*)&Xs[base + 32] = sp;
            *(short8*)&Xs[base + 48] = zz;
            if (!half) {
                float dx = R[bi*3+0] - R[rowj*3+0];
                float dy = R[bi*3+1] - R[rowj*3+1];
                float dz = R[bi*3+2] - R[rowj*3+2];
                r_s[pl] = sqrtf(dx*dx + dy*dy + dz*dz + 1e-12f);
            }
        }
        __syncthreads();

        // ---- GEMM1: H1 = relu(X @ W1 + b1) ----
        #pragma unroll
        for (int mt = 0; mt < 8; mt++) {
            int arow = (mt*16 + l15)*72 + q*8;
            short8 a0 = *(const short8*)&Xs[arow];
            short8 a1 = *(const short8*)&Xs[arow + 32];
            #pragma unroll
            for (int nt = 0; nt < 2; nt++) {
                floatx4 acc = {0.f, 0.f, 0.f, 0.f};
                acc = __builtin_amdgcn_mfma_f32_16x16x32_bf16(a0, w1f[nt][0], acc, 0, 0, 0);
                acc = __builtin_amdgcn_mfma_f32_16x16x32_bf16(a1, w1f[nt][1], acc, 0, 0, 0);
                int col = (2*wv + nt)*16 + l15;
                int r0  = mt*16 + q*4;
                #pragma unroll
                for (int d = 0; d < 4; d++)
                    Hs[(r0+d)*136 + col] = f2bf(fmaxf(acc[d] + b1v[nt], 0.f));
            }
        }
        __syncthreads();

        // ---- GEMM2: H2 = relu(H1 @ W2 + b2); hold in regs until all reads done ----
        floatx4 acc2[8][2];
        #pragma unroll
        for (int mt = 0; mt < 8; mt++) {
            int arow = (mt*16 + l15)*136 + q*8;
            short8 h0 = *(const short8*)&Hs[arow];
            short8 h1f = *(const short8*)&Hs[arow + 32];
            short8 h2f = *(const short8*)&Hs[arow + 64];
            short8 h3f = *(const short8*)&Hs[arow + 96];
            #pragma unroll
            for (int nt = 0; nt < 2; nt++) {
                floatx4 acc = {0.f, 0.f, 0.f, 0.f};
                acc = __builtin_amdgcn_mfma_f32_16x16x32_bf16(h0,  w2f[nt][0], acc, 0, 0, 0);
                acc = __builtin_amdgcn_mfma_f32_16x16x32_bf16(h1f, w2f[nt][1], acc, 0, 0, 0);
                acc = __builtin_amdgcn_mfma_f32_16x16x32_bf16(h2f, w2f[nt][2], acc, 0, 0, 0);
                acc = __builtin_amdgcn_mfma_f32_16x16x32_bf16(h3f, w2f[nt][3], acc, 0, 0, 0);
                acc2[mt][nt] = acc;
            }
        }
        __syncthreads();
        #pragma unroll
        for (int mt = 0; mt < 8; mt++)
            #pragma unroll
            for (int nt = 0; nt < 2; nt++) {
                int col = (2*wv + nt)*16 + l15;
                int r0  = mt*16 + q*4;
                #pragma unroll
                for (int d = 0; d < 4; d++)
                    Hs[(r0+d)*136 + col] = f2bf(fmaxf(acc2[mt][nt][d] + b2v[nt], 0.f));
            }
        __syncthreads();

        // ---- GEMM3 (H2 @ W3, N padded to 16) + epilogue ----
        float esum = 0.f;
        #pragma unroll
        for (int mi = 0; mi < 2; mi++) {
            int mt = 2*wv + mi;
            int arow = (mt*16 + l15)*136 + q*8;
            floatx4 acc = {0.f, 0.f, 0.f, 0.f};
            #pragma unroll
            for (int kt = 0; kt < 4; kt++) {
                short8 af = *(const short8*)&Hs[arow + kt*32];
                acc = __builtin_amdgcn_mfma_f32_16x16x32_bf16(af, w3f[kt], acc, 0, 0, 0);
            }
            float att[4], rr[4];
            #pragma unroll
            for (int d = 0; d < 4; d++) {
                rr[d] = r_s[mt*16 + q*4 + d];
                float logit = acc[d] + b3v;
                float sp = fmaxf(logit, 0.f) + log1pf(expf(-fabsf(logit)));
                float dd = rr[d] - cen;
                float phi = expf(-dd*dd*i2w);
                att[d] = (l15 < MRBF) ? sp*phi : 0.f;
            }
            #pragma unroll
            for (int off = 1; off <= 8; off <<= 1)
                #pragma unroll
                for (int d = 0; d < 4; d++)
                    att[d] += __shfl_xor(att[d], off, 16);
            #pragma unroll
            for (int d = 0; d < 4; d++) {
                float t = fminf(fmaxf((rr[d] - 10.f)*0.5f, 0.f), 1.f);
                float sw = 1.f - t*t*(3.f - 2.f*t);
                esum += -att[d]*sw;
            }
        }
        // att duplicated across 16 lanes of each quad -> sum the 4 quads
        esum += __shfl_xor(esum, 16, 64);
        esum += __shfl_xor(esum, 32, 64);
        if (lane == 0) atomicAdd(&bacc[tile >> 10], esum);
    }
    __syncthreads();
    if (tid < BATCH) atomicAdd(&out[tid], bacc[tid]);
}

// ---------------------------------------------------------------------------
extern "C" void kernel_launch(void* const* d_in, const int* in_sizes, int n_in,
                              void* d_out, int out_size, void* d_ws, size_t ws_size,
                              hipStream_t stream) {
    const float* R       = (const float*)d_in[0];
    const int*   seq     = (const int*)  d_in[1];
    const float* emb     = (const float*)d_in[2];
    const float* W1      = (const float*)d_in[3];
    const float* b1      = (const float*)d_in[4];
    const float* W2      = (const float*)d_in[5];
    const float* b2      = (const float*)d_in[6];
    const float* W3      = (const float*)d_in[7];
    const float* b3      = (const float*)d_in[8];
    const float* centers = (const float*)d_in[9];
    const float* widths  = (const float*)d_in[10];
    float* out = (float*)d_out;
    int*   nbr = (int*)d_ws;   // BATCH*LSEQ*KNB ints = 4 MiB

    hipMemsetAsync(d_out, 0, out_size * sizeof(float), stream);

    topk_kernel<<<BATCH*LSEQ, 256, 0, stream>>>(R, nbr);
    mlp_mfma_kernel<<<2048, 256, 0, stream>>>(R, seq, emb, W1, b1, W2, b2, W3, b3,
                                              centers, widths, nbr, out);
}

// Round 3
// 299.599 us; speedup vs baseline: 10.8434x; 1.2794x over previous
//
#include <hip/hip_runtime.h>
#include <math.h>

#define LSEQ 2048
#define KNB 64
#define BATCH 8
#define MRBF 7
#define NPAIRS (BATCH*LSEQ*KNB)
#define NTILES (NPAIRS/128)
#define XST 68    // X LDS stride (bf16 elems): 64 + 4 pad, b64-aligned reads
#define HST 136   // H LDS stride: 128 + 8 pad, b128-aligned reads
#define NBINS 2048
#define D2CUT 144.0f
#define KSCALE (2047.0f/144.0f)

typedef __attribute__((ext_vector_type(8))) short short8;
typedef __attribute__((ext_vector_type(4))) float floatx4;

__device__ __forceinline__ unsigned short f2bf(float f) {
    unsigned u = __float_as_uint(f);
    u += 0x7fffu + ((u >> 16) & 1u);
    return (unsigned short)(u >> 16);
}
// packed round-half-up bf16x2 (5 ops); values here are bounded, no inf/nan
__device__ __forceinline__ unsigned pkbf(float a, float b) {
    return ((__float_as_uint(a) + 0x8000u) >> 16) |
           ((__float_as_uint(b) + 0x8000u) & 0xffff0000u);
}

// ---------------------------------------------------------------------------
// Kernel 1: top-K=64 via single-pass 2048-bin histogram select.
// Exact for all pairs with d2 < 144 (r < 12); pairs beyond contribute exactly
// 0 (smoothstep), so the fill set there is arbitrary (finite-d2 = non-bonded).
// Keys/d2 stay in registers: one pass over data, one scan, one compaction.
// ---------------------------------------------------------------------------
__global__ __launch_bounds__(256) void topk_kernel(
    const float* __restrict__ R, int* __restrict__ nbr)
{
    const int bi = blockIdx.x;
    const int i  = bi & (LSEQ - 1);
    const int bL = bi & ~(LSEQ - 1);
    const int tid  = threadIdx.x;
    const int lane = tid & 63;
    const int wv   = tid >> 6;

    __shared__ unsigned hist[NBINS];
    __shared__ unsigned cumw[4];
    __shared__ int s_B;
    __shared__ unsigned s_below;
    __shared__ int outPos, candCnt, fillCnt;
    __shared__ float cand_d2[512];
    __shared__ int   cand_idx[512];

    #pragma unroll
    for (int u = 0; u < 8; u++) hist[tid + 256*u] = 0u;
    if (tid == 0) { outPos = 0; candCnt = 0; fillCnt = 0; }

    const float xi = R[bi*3+0], yi = R[bi*3+1], zi = R[bi*3+2];
    float d2r[8]; int keyr[8];
    __syncthreads();

    #pragma unroll
    for (int u = 0; u < 8; u++) {
        int j = tid + 256*u;
        float dx = xi - R[(bL+j)*3+0];
        float dy = yi - R[(bL+j)*3+1];
        float dz = zi - R[(bL+j)*3+2];
        float d2 = dx*dx + dy*dy + dz*dz;
        int dd = j - i; dd = dd < 0 ? -dd : dd;
        if (dd <= 3) d2 = __uint_as_float(0x7f800000u);   // bonded -> +inf
        int key = (d2 < D2CUT) ? (int)(d2 * KSCALE) : (NBINS - 1);
        d2r[u] = d2; keyr[u] = key;
        atomicAdd(&hist[key], 1u);
    }
    __syncthreads();

    // scan: thread t owns bins [8t, 8t+8); wave shfl-scan; 4-entry cross-wave
    unsigned s = 0;
    #pragma unroll
    for (int v = 0; v < 8; v++) s += hist[8*tid + v];
    unsigned inc = s;
    #pragma unroll
    for (int off = 1; off < 64; off <<= 1) {
        unsigned n = __shfl_up(inc, off, 64);
        if (lane >= off) inc += n;
    }
    if (lane == 63) cumw[wv] = inc;
    __syncthreads();
    unsigned woff = 0;
    for (int w = 0; w < wv; w++) woff += cumw[w];
    unsigned excl = woff + inc - s;
    if (excl < 64u && 64u <= excl + s) {
        unsigned c = excl;
        #pragma unroll
        for (int v = 0; v < 8; v++) {
            unsigned h = hist[8*tid + v];
            if (c < 64u && 64u <= c + h) { s_B = 8*tid + v; s_below = c; }
            c += h;
        }
    }
    __syncthreads();
    const int B = s_B;
    const int need = 64 - (int)s_below;
    const int outBase = bi * KNB;

    #pragma unroll
    for (int u = 0; u < 8; u++) {
        int j = tid + 256*u;
        int k = keyr[u];
        if (k < B) {
            int pos = atomicAdd(&outPos, 1);
            nbr[outBase + pos] = j;
        } else if (k == B) {
            if (B == NBINS - 1) {
                // fewer than 64 inside cutoff: any finite-d2 (non-bonded) filler
                // has r >= 12 -> smooth_switch == 0 -> contributes exactly 0
                if (d2r[u] < 3.0e38f) {
                    int t = atomicAdd(&fillCnt, 1);
                    if (t < need) { int pos = atomicAdd(&outPos, 1); nbr[outBase + pos] = j; }
                }
            } else {
                int c = atomicAdd(&candCnt, 1);
                if (c < 512) { cand_d2[c] = d2r[u]; cand_idx[c] = j; }
            }
        }
    }
    __syncthreads();
    if (B != NBINS - 1) {
        // exact rank among boundary-bin members (typically 0-4 elements)
        int c = candCnt; if (c > 512) c = 512;
        for (int ci = tid; ci < c; ci += 256) {
            float dv = cand_d2[ci]; int jv = cand_idx[ci];
            int rank = 0;
            for (int x = 0; x < c; x++) {
                float dx2 = cand_d2[x]; int jx = cand_idx[x];
                rank += (dx2 < dv) || (dx2 == dv && jx < jv);
            }
            if (rank < need) { int pos = atomicAdd(&outPos, 1); nbr[outBase + pos] = jv; }
        }
    }
}

// ---------------------------------------------------------------------------
// Kernel 2: pair MLP via bf16 MFMA, operand-swapped: D = W^T (A) @ X^T (B),
// so D rows = neurons (q*4+d contiguous) and cols = pairs (l15). Each lane's
// 4 outputs are contiguous in the [pair][neuron] LDS layout -> one packed
// ds_write_b64 (bank-uniform) instead of 4 scalar column writes. The same
// layout is directly the B-fragment source of the next GEMM (b128 reads).
// ---------------------------------------------------------------------------
__global__ __launch_bounds__(256, 3) void mlp_mfma_kernel(
    const float* __restrict__ R, const int* __restrict__ seq,
    const float* __restrict__ emb,
    const float* __restrict__ W1, const float* __restrict__ b1,
    const float* __restrict__ W2, const float* __restrict__ b2,
    const float* __restrict__ W3, const float* __restrict__ b3,
    const float* __restrict__ centers, const float* __restrict__ widths,
    const int* __restrict__ nbr, float* __restrict__ out)
{
    __shared__ __align__(16) unsigned short Xs[128*XST];   // 17408 B
    __shared__ __align__(16) unsigned short Hs[128*HST];   // 34816 B
    __shared__ float r_s[128];
    __shared__ float bacc[BATCH];

    const int tid  = threadIdx.x;
    const int lane = tid & 63;
    const int wv   = tid >> 6;
    const int l15  = lane & 15;
    const int q    = lane >> 4;

    // ---- persistent A-operand (transposed-weight) register fragments ----
    // A[m][k]: m = lane&15 (output neuron), k = quad*8+j
    short8 w1f[2][2], w2f[2][4], w3f[4];
    float b1v[2][4], b2v[2][4];
    #pragma unroll
    for (int mtl = 0; mtl < 2; mtl++) {
        int m = (2*wv + mtl)*16 + l15;
        #pragma unroll
        for (int d = 0; d < 4; d++) {
            b1v[mtl][d] = b1[(2*wv + mtl)*16 + q*4 + d];
            b2v[mtl][d] = b2[(2*wv + mtl)*16 + q*4 + d];
        }
        #pragma unroll
        for (int kt = 0; kt < 2; kt++)
            #pragma unroll
            for (int j = 0; j < 8; j++) {
                int k = kt*32 + q*8 + j;
                w1f[mtl][kt][j] = (short)((k < 48) ? f2bf(W1[k*128 + m]) : 0);
            }
        #pragma unroll
        for (int kt = 0; kt < 4; kt++)
            #pragma unroll
            for (int j = 0; j < 8; j++) {
                int k = kt*32 + q*8 + j;
                w2f[mtl][kt][j] = (short)f2bf(W2[k*128 + m]);
            }
    }
    #pragma unroll
    for (int kt = 0; kt < 4; kt++)
        #pragma unroll
        for (int j = 0; j < 8; j++) {
            int k = kt*32 + q*8 + j;
            w3f[kt][j] = (short)((l15 < MRBF) ? f2bf(W3[k*MRBF + l15]) : 0);
        }
    float b3v[4], cen[4], i2w[4];
    #pragma unroll
    for (int d = 0; d < 4; d++) {
        int rb = q*4 + d;
        bool ok = rb < MRBF;
        b3v[d] = ok ? b3[rb] : 0.f;
        cen[d] = ok ? centers[rb] : 0.f;
        float wd = ok ? widths[rb] : 1.f;
        i2w[d] = 0.5f / (wd*wd);
    }
    if (tid < BATCH) bacc[tid] = 0.f;

    for (int tile = blockIdx.x; tile < NTILES; tile += gridDim.x) {
        __syncthreads();   // previous tile's readers done; bacc init visible

        // ---- build X^T source: Xs[pair][feature], bf16, zero-pad 48..63 ----
        {
            int pl = tid >> 1, half = tid & 1;
            int p  = tile*128 + pl;
            int bi = p >> 6;
            int b  = p >> 17;
            int jn = nbr[p];
            int rowj = (b << 11) + jn;
            int si = seq[bi], sj = seq[rowj];
            const float* ei = emb + si*16 + half*8;
            const float* ej = emb + sj*16 + half*8;
            float a0[8], c0[8];
            #pragma unroll
            for (int f = 0; f < 8; f++) { a0[f] = ei[f]; c0[f] = ej[f]; }
            int base = pl*XST + half*8;   // b16 units; byte addr % 8 == 0
            uint2* pe = (uint2*)&Xs[base];
            pe[0] = make_uint2(pkbf(a0[0],a0[1]), pkbf(a0[2],a0[3]));
            pe[1] = make_uint2(pkbf(a0[4],a0[5]), pkbf(a0[6],a0[7]));
            uint2* pn = (uint2*)&Xs[base + 16];
            pn[0] = make_uint2(pkbf(c0[0],c0[1]), pkbf(c0[2],c0[3]));
            pn[1] = make_uint2(pkbf(c0[4],c0[5]), pkbf(c0[6],c0[7]));
            uint2* pp = (uint2*)&Xs[base + 32];
            pp[0] = make_uint2(pkbf(a0[0]*c0[0],a0[1]*c0[1]), pkbf(a0[2]*c0[2],a0[3]*c0[3]));
            pp[1] = make_uint2(pkbf(a0[4]*c0[4],a0[5]*c0[5]), pkbf(a0[6]*c0[6],a0[7]*c0[7]));
            uint2* pz = (uint2*)&Xs[base + 48];
            pz[0] = make_uint2(0u, 0u);
            pz[1] = make_uint2(0u, 0u);
            if (!half) {
                float dx = R[bi*3+0] - R[rowj*3+0];
                float dy = R[bi*3+1] - R[rowj*3+1];
                float dz = R[bi*3+2] - R[rowj*3+2];
                r_s[pl] = sqrtf(dx*dx + dy*dy + dz*dz + 1e-12f);
            }
        }
        __syncthreads();

        // ---- GEMM1: H1^T-block = W1^T @ X^T, write packed b64 ----
        #pragma unroll
        for (int nt = 0; nt < 8; nt++) {
            const unsigned long long* px =
                (const unsigned long long*)&Xs[(nt*16 + l15)*XST];
            short8 xf[2];
            #pragma unroll
            for (int kt = 0; kt < 2; kt++) {
                union { short8 s; unsigned long long u[2]; } t;
                t.u[0] = px[kt*8 + 0];
                t.u[1] = px[kt*8 + 1];
                xf[kt] = t.s;
            }
            #pragma unroll
            for (int mtl = 0; mtl < 2; mtl++) {
                floatx4 acc = {0.f, 0.f, 0.f, 0.f};
                acc = __builtin_amdgcn_mfma_f32_16x16x32_bf16(w1f[mtl][0], xf[0], acc, 0, 0, 0);
                acc = __builtin_amdgcn_mfma_f32_16x16x32_bf16(w1f[mtl][1], xf[1], acc, 0, 0, 0);
                float v0 = fmaxf(acc[0] + b1v[mtl][0], 0.f);
                float v1 = fmaxf(acc[1] + b1v[mtl][1], 0.f);
                float v2 = fmaxf(acc[2] + b1v[mtl][2], 0.f);
                float v3 = fmaxf(acc[3] + b1v[mtl][3], 0.f);
                *(uint2*)&Hs[(nt*16 + l15)*HST + (2*wv + mtl)*16 + q*4] =
                    make_uint2(pkbf(v0,v1), pkbf(v2,v3));
            }
        }
        __syncthreads();

        // ---- GEMM2: read H1, hold relu+packed H2 in regs across barrier ----
        uint2 h2p[8][2];
        #pragma unroll
        for (int nt = 0; nt < 8; nt++) {
            const unsigned short* ph = &Hs[(nt*16 + l15)*HST];
            short8 hf[4];
            #pragma unroll
            for (int kt = 0; kt < 4; kt++)
                hf[kt] = *(const short8*)&ph[kt*32];
            #pragma unroll
            for (int mtl = 0; mtl < 2; mtl++) {
                floatx4 acc = {0.f, 0.f, 0.f, 0.f};
                acc = __builtin_amdgcn_mfma_f32_16x16x32_bf16(w2f[mtl][0], hf[0], acc, 0, 0, 0);
                acc = __builtin_amdgcn_mfma_f32_16x16x32_bf16(w2f[mtl][1], hf[1], acc, 0, 0, 0);
                acc = __builtin_amdgcn_mfma_f32_16x16x32_bf16(w2f[mtl][2], hf[2], acc, 0, 0, 0);
                acc = __builtin_amdgcn_mfma_f32_16x16x32_bf16(w2f[mtl][3], hf[3], acc, 0, 0, 0);
                float v0 = fmaxf(acc[0] + b2v[mtl][0], 0.f);
                float v1 = fmaxf(acc[1] + b2v[mtl][1], 0.f);
                float v2 = fmaxf(acc[2] + b2v[mtl][2], 0.f);
                float v3 = fmaxf(acc[3] + b2v[mtl][3], 0.f);
                h2p[nt][mtl] = make_uint2(pkbf(v0,v1), pkbf(v2,v3));
            }
        }
        __syncthreads();   // all H1 reads complete
        #pragma unroll
        for (int nt = 0; nt < 8; nt++)
            #pragma unroll
            for (int mtl = 0; mtl < 2; mtl++)
                *(uint2*)&Hs[(nt*16 + l15)*HST + (2*wv + mtl)*16 + q*4] = h2p[nt][mtl];
        __syncthreads();

        // ---- GEMM3 (W3^T @ H2^T) + epilogue; wave owns pair-tiles 2wv,2wv+1 ----
        float esum = 0.f;
        #pragma unroll
        for (int ntl = 0; ntl < 2; ntl++) {
            int nt = 2*wv + ntl;
            const unsigned short* ph = &Hs[(nt*16 + l15)*HST];
            floatx4 acc = {0.f, 0.f, 0.f, 0.f};
            #pragma unroll
            for (int kt = 0; kt < 4; kt++) {
                short8 hf = *(const short8*)&ph[kt*32];
                acc = __builtin_amdgcn_mfma_f32_16x16x32_bf16(w3f[kt], hf, acc, 0, 0, 0);
            }
            float rr = r_s[nt*16 + l15];
            if (rr < 12.0f) {      // uniform within each xor16/32 shuffle group
                float att = 0.f;
                #pragma unroll
                for (int d = 0; d < 4; d++) {
                    if (q*4 + d < MRBF) {
                        float x = acc[d] + b3v[d];
                        float sp = fmaxf(x, 0.f) + __logf(1.f + __expf(-fabsf(x)));
                        float dd = rr - cen[d];
                        att += sp * __expf(-dd*dd*i2w[d]);
                    }
                }
                att += __shfl_xor(att, 16, 64);
                att += __shfl_xor(att, 32, 64);
                float t = fminf(fmaxf((rr - 10.f)*0.5f, 0.f), 1.f);
                float sw = 1.f - t*t*(3.f - 2.f*t);
                esum -= att * sw;   // 4x replicated across quads; /4 at the end
            }
        }
        #pragma unroll
        for (int off = 1; off < 64; off <<= 1)
            esum += __shfl_xor(esum, off, 64);
        if (lane == 0) atomicAdd(&bacc[tile >> 10], esum * 0.25f);
    }
    __syncthreads();
    if (tid < BATCH) atomicAdd(&out[tid], bacc[tid]);
}

// ---------------------------------------------------------------------------
extern "C" void kernel_launch(void* const* d_in, const int* in_sizes, int n_in,
                              void* d_out, int out_size, void* d_ws, size_t ws_size,
                              hipStream_t stream) {
    const float* R       = (const float*)d_in[0];
    const int*   seq     = (const int*)  d_in[1];
    const float* emb     = (const float*)d_in[2];
    const float* W1      = (const float*)d_in[3];
    const float* b1      = (const float*)d_in[4];
    const float* W2      = (const float*)d_in[5];
    const float* b2      = (const float*)d_in[6];
    const float* W3      = (const float*)d_in[7];
    const float* b3      = (const float*)d_in[8];
    const float* centers = (const float*)d_in[9];
    const float* widths  = (const float*)d_in[10];
    float* out = (float*)d_out;
    int*   nbr = (int*)d_ws;   // NPAIRS ints = 4 MiB

    hipMemsetAsync(d_out, 0, out_size * sizeof(float), stream);

    topk_kernel<<<BATCH*LSEQ, 256, 0, stream>>>(R, nbr);
    mlp_mfma_kernel<<<2048, 256, 0, stream>>>(R, seq, emb, W1, b1, W2, b2, W3, b3,
                                              centers, widths, nbr, out);
}